// Round 1
// baseline (2543.716 us; speedup 1.0000x reference)
//
#include <hip/hip_runtime.h>

// LSTM cell, B=8192, I=H=2048, fp32 in/out.
// Strategy: fp16 hi/lo split GEMM (3-term) on MFMA 16x16x32_f16,
// m97-style 128x128 tile, global_load_lds staging, fused gate epilogue.

#define PLANE 16777216   // 8192*2048 elements per [B,H] plane
#define LDK   2048       // K per segment (= I = H)

typedef _Float16 h8_t __attribute__((ext_vector_type(8)));
typedef _Float16 h4_t __attribute__((ext_vector_type(4)));
typedef float    f32x4 __attribute__((ext_vector_type(4)));

__device__ __forceinline__ float fast_sigmoid(float x) {
  return 1.0f / (1.0f + __expf(-x));
}
__device__ __forceinline__ float fast_tanh(float x) {
  // tanh(x) = 1 - 2/(e^{2x}+1); exact limits at +-inf, fine near 0.
  float e = __expf(2.0f * x);
  return 1.0f - 2.0f / (e + 1.0f);
}

// ---------------- split: fp32 -> (hi, lo) fp16 ----------------
__global__ void split_kernel(const float* __restrict__ src,
                             _Float16* __restrict__ hi,
                             _Float16* __restrict__ lo, int n) {
  int idx = (blockIdx.x * blockDim.x + threadIdx.x) * 4;
  int stride = gridDim.x * blockDim.x * 4;
  for (int i = idx; i < n; i += stride) {
    float4 v = *reinterpret_cast<const float4*>(src + i);
    _Float16 h0 = (_Float16)v.x, h1 = (_Float16)v.y,
             h2 = (_Float16)v.z, h3 = (_Float16)v.w;
    h4_t hv = {h0, h1, h2, h3};
    h4_t lv = {(_Float16)(v.x - (float)h0), (_Float16)(v.y - (float)h1),
               (_Float16)(v.z - (float)h2), (_Float16)(v.w - (float)h3)};
    *reinterpret_cast<h4_t*>(hi + i) = hv;
    *reinterpret_cast<h4_t*>(lo + i) = lv;
  }
}

// ---------------- GEMM + gate-activation epilogue ----------------
__device__ __forceinline__ void gload_lds16(const _Float16* g, _Float16* l) {
  __builtin_amdgcn_global_load_lds(
      (const __attribute__((address_space(1))) void*)g,
      (__attribute__((address_space(3))) void*)l, 16, 0, 0);
}

__global__ __launch_bounds__(256) void gemm_gates_kernel(
    const _Float16* __restrict__ xh, const _Float16* __restrict__ xl,
    const _Float16* __restrict__ hh, const _Float16* __restrict__ hl,
    const _Float16* __restrict__ Wh, const _Float16* __restrict__ Wl,
    const _Float16* __restrict__ Uh, const _Float16* __restrict__ Ul,
    const float* __restrict__ bias,
    float* __restrict__ out, _Float16* __restrict__ o_ws) {
  __shared__ _Float16 sA[128 * 64];
  __shared__ _Float16 sB[128 * 64];

  // XCD-aware swizzle: nwg = 4096, divisible by 8 -> simple bijection.
  const int bid = blockIdx.x;
  const int wg = (bid & 7) * 512 + (bid >> 3);
  const int tm = wg & 63;   // row tile (batch)
  const int tn = wg >> 6;   // col tile (gate*H)

  const int tid = threadIdx.x;
  const int wave = tid >> 6;
  const int lane = tid & 63;
  const int wr = wave >> 1;   // wave row quadrant (0..1)
  const int wc = wave & 1;    // wave col quadrant (0..1)

  // Staging geometry: tile is 128 rows x 64 k (f16), 1024 x 16B chunks.
  // chunk ch = j*256 + tid ; row = ch>>3 ; col8 = ch&7.
  int gOffA[4], gOffB[4];
#pragma unroll
  for (int j = 0; j < 4; ++j) {
    int ch = j * 256 + tid;
    int r = ch >> 3;
    int c = (ch & 7) * 8;
    gOffA[j] = (tm * 128 + r) * LDK + c;
    gOffB[j] = (tn * 128 + r) * LDK + c;
  }

  f32x4 acc[4][4];
#pragma unroll
  for (int m = 0; m < 4; ++m)
#pragma unroll
    for (int n = 0; n < 4; ++n)
      acc[m][n] = (f32x4){0.f, 0.f, 0.f, 0.f};

  const int aRow = wr * 64 + (lane & 15);
  const int bRow = wc * 64 + (lane & 15);
  const int kHi = (lane >> 4) * 8;

  // 6 K-segments of 2048: (xh,Wh) (xl,Wh) (xh,Wl) (hh,Uh) (hl,Uh) (hh,Ul)
#pragma unroll
  for (int s = 0; s < 6; ++s) {
    const _Float16* Aseg = (s == 1) ? xl : (s == 4) ? hl : (s < 3) ? xh : hh;
    const _Float16* Bseg = (s < 2) ? Wh : (s == 2) ? Wl : (s < 5) ? Uh : Ul;
    for (int t = 0; t < 32; ++t) {
      const int k0 = t * 64;
      __syncthreads();  // previous compute done before overwrite
#pragma unroll
      for (int j = 0; j < 4; ++j) {
        gload_lds16(Aseg + gOffA[j] + k0, sA + j * 2048 + wave * 512);
        gload_lds16(Bseg + gOffB[j] + k0, sB + j * 2048 + wave * 512);
      }
      __syncthreads();  // compiler drains vmcnt(0) before barrier
#pragma unroll
      for (int kk = 0; kk < 2; ++kk) {
        h8_t af[4], bf[4];
#pragma unroll
        for (int m = 0; m < 4; ++m)
          af[m] = *reinterpret_cast<const h8_t*>(
              &sA[(aRow + m * 16) * 64 + kk * 32 + kHi]);
#pragma unroll
        for (int n = 0; n < 4; ++n)
          bf[n] = *reinterpret_cast<const h8_t*>(
              &sB[(bRow + n * 16) * 64 + kk * 32 + kHi]);
#pragma unroll
        for (int m = 0; m < 4; ++m)
#pragma unroll
          for (int n = 0; n < 4; ++n)
            acc[m][n] = __builtin_amdgcn_mfma_f32_16x16x32_f16(
                af[m], bf[n], acc[m][n], 0, 0, 0);
      }
    }
  }

  // Epilogue: C/D layout col=lane&15, row=(lane>>4)*4+reg (m89-verified).
  // gate = which quarter of N we are in; uniform per block (128 | 2048).
  const int gate = tn >> 4;
  const int row0 = tm * 128 + wr * 64 + (lane >> 4) * 4;
  const int col0 = tn * 128 + wc * 64 + (lane & 15);
#pragma unroll
  for (int n = 0; n < 4; ++n) {
    const int col = col0 + n * 16;
    const int hcol = col & 2047;
    const float bv = bias[col];
#pragma unroll
    for (int m = 0; m < 4; ++m) {
      const int row = row0 + m * 16;
#pragma unroll
      for (int r = 0; r < 4; ++r) {
        float v = acc[m][n][r] + bv;
        size_t oidx = (size_t)(row + r) * 2048 + hcol;
        if (gate == 0)       out[(size_t)3 * PLANE + oidx] = fast_sigmoid(v);  // f_t
        else if (gate == 1)  out[(size_t)2 * PLANE + oidx] = fast_sigmoid(v);  // i_t
        else if (gate == 2)  out[(size_t)4 * PLANE + oidx] = fast_tanh(v);     // C~_t
        else                 o_ws[oidx] = (_Float16)fast_sigmoid(v);           // o_t
      }
    }
  }
}

// ---------------- final: C_t and h_t ----------------
__global__ void final_kernel(const float* __restrict__ outr,
                             const float* __restrict__ C_prev,
                             const _Float16* __restrict__ o_ws,
                             float* __restrict__ out) {
  const float* iP = outr + (size_t)2 * PLANE;
  const float* fP = outr + (size_t)3 * PLANE;
  const float* cP = outr + (size_t)4 * PLANE;
  int idx = (blockIdx.x * blockDim.x + threadIdx.x) * 4;
  int stride = gridDim.x * blockDim.x * 4;
  for (int i = idx; i < PLANE; i += stride) {
    float4 fv = *reinterpret_cast<const float4*>(fP + i);
    float4 iv = *reinterpret_cast<const float4*>(iP + i);
    float4 cv = *reinterpret_cast<const float4*>(cP + i);
    float4 cp = *reinterpret_cast<const float4*>(C_prev + i);
    h4_t ov = *reinterpret_cast<const h4_t*>(o_ws + i);
    float4 C, H;
    C.x = fv.x * cp.x + iv.x * cv.x;
    C.y = fv.y * cp.y + iv.y * cv.y;
    C.z = fv.z * cp.z + iv.z * cv.z;
    C.w = fv.w * cp.w + iv.w * cv.w;
    H.x = (float)ov.x * fast_tanh(C.x);
    H.y = (float)ov.y * fast_tanh(C.y);
    H.z = (float)ov.z * fast_tanh(C.z);
    H.w = (float)ov.w * fast_tanh(C.w);
    *reinterpret_cast<float4*>(out + (size_t)PLANE + i) = C;  // C_t
    *reinterpret_cast<float4*>(out + i) = H;                  // h_t
  }
}

extern "C" void kernel_launch(void* const* d_in, const int* in_sizes, int n_in,
                              void* d_out, int out_size, void* d_ws, size_t ws_size,
                              hipStream_t stream) {
  const float* x  = (const float*)d_in[0];
  const float* hp = (const float*)d_in[1];
  const float* Cp = (const float*)d_in[2];
  const float* W  = (const float*)d_in[3];
  const float* U  = (const float*)d_in[4];
  const float* b  = (const float*)d_in[5];
  float* out = (float*)d_out;

  _Float16* ws = (_Float16*)d_ws;
  _Float16* xh = ws;
  _Float16* xl = xh + PLANE;
  _Float16* hh = xl + PLANE;
  _Float16* hl = hh + PLANE;
  _Float16* Wh = hl + PLANE;
  _Float16* Wl = Wh + PLANE;
  _Float16* Uh = Wl + PLANE;
  _Float16* Ul = Uh + PLANE;
  _Float16* o_ws = Ul + PLANE;  // total ws use: 9 * 32 MiB = 288 MiB + pad

  dim3 blk(256);
  split_kernel<<<dim3(2048), blk, 0, stream>>>(x, xh, xl, PLANE);
  split_kernel<<<dim3(2048), blk, 0, stream>>>(hp, hh, hl, PLANE);
  split_kernel<<<dim3(2048), blk, 0, stream>>>(W, Wh, Wl, PLANE);
  split_kernel<<<dim3(2048), blk, 0, stream>>>(U, Uh, Ul, PLANE);
  gemm_gates_kernel<<<dim3(4096), blk, 0, stream>>>(xh, xl, hh, hl, Wh, Wl,
                                                    Uh, Ul, b, out, o_ws);
  final_kernel<<<dim3(2048), blk, 0, stream>>>(out, Cp, o_ws, out);
}

// Round 2
// 2001.434 us; speedup vs baseline: 1.2709x; 1.2709x over previous
//
#include <hip/hip_runtime.h>

// LSTM cell, B=8192, I=H=2048, fp32 in/out.
// fp16 hi/lo 3-term split GEMM on MFMA 16x16x32_f16.
// 256x256 tile, BK=64, 8 waves, 8-phase-style schedule with counted vmcnt(6),
// XOR-swizzled LDS (both-sides involution), setprio around MFMA clusters.

#define PLANE 16777216   // 8192*2048 elements per [B,H] plane
#define T_TILES 192      // 6 segments x 32 K-tiles of 64

typedef _Float16 h8_t __attribute__((ext_vector_type(8)));
typedef _Float16 h4_t __attribute__((ext_vector_type(4)));
typedef float    f32x4 __attribute__((ext_vector_type(4)));

#define BARRIER() do { asm volatile("" ::: "memory"); \
                       __builtin_amdgcn_s_barrier();  \
                       asm volatile("" ::: "memory"); } while (0)

__device__ __forceinline__ float fast_sigmoid(float x) {
  return 1.0f / (1.0f + __expf(-x));
}
__device__ __forceinline__ float fast_tanh(float x) {
  float e = __expf(2.0f * x);
  return 1.0f - 2.0f / (e + 1.0f);
}

// ---------------- split: fp32 -> (hi, lo) fp16 ----------------
__global__ void split_kernel(const float* __restrict__ src,
                             _Float16* __restrict__ hi,
                             _Float16* __restrict__ lo, int n) {
  int idx = (blockIdx.x * blockDim.x + threadIdx.x) * 4;
  int stride = gridDim.x * blockDim.x * 4;
  for (int i = idx; i < n; i += stride) {
    float4 v = *reinterpret_cast<const float4*>(src + i);
    _Float16 h0 = (_Float16)v.x, h1 = (_Float16)v.y,
             h2 = (_Float16)v.z, h3 = (_Float16)v.w;
    h4_t hv = {h0, h1, h2, h3};
    h4_t lv = {(_Float16)(v.x - (float)h0), (_Float16)(v.y - (float)h1),
               (_Float16)(v.z - (float)h2), (_Float16)(v.w - (float)h3)};
    *reinterpret_cast<h4_t*>(hi + i) = hv;
    *reinterpret_cast<h4_t*>(lo + i) = lv;
  }
}

// ---------------- GEMM helpers ----------------
__device__ __forceinline__ void gload_lds16(const _Float16* g, _Float16* l) {
  __builtin_amdgcn_global_load_lds(
      (const __attribute__((address_space(1))) void*)g,
      (__attribute__((address_space(3))) void*)l, 16, 0, 0);
}

// Stage one half-tile (128 rows x 64 k f16 = 16KiB) with pre-swizzled global
// source so LDS-linear dest + swizzled ds_read form a consistent involution.
__device__ __forceinline__ void stage_half(const _Float16* __restrict__ seg,
                                           int rowBase, int k0,
                                           _Float16* lds, int hh, int tid) {
#pragma unroll
  for (int j = 0; j < 2; ++j) {
    const int c = j * 512 + tid;          // 0..1023 16B-chunks
    const int r = c >> 3;                 // row in half 0..127
    const int colb = (c & 7) << 4;        // byte col 0..112
    const int sw = colb ^ ((r & 7) << 4); // involutive XOR swizzle
    const _Float16* g = seg + (size_t)(rowBase + hh * 128 + r) * 2048 + k0 + (sw >> 1);
    gload_lds16(g, lds + hh * 8192 + c * 8);
  }
}

__device__ __forceinline__ const _Float16* segA(int kt,
    const _Float16* xH, const _Float16* xL,
    const _Float16* hH, const _Float16* hL) {
  int s = kt >> 5;
  return s == 0 ? xH : s == 1 ? xL : s == 2 ? xH : s == 3 ? hH : s == 4 ? hL : hH;
}
__device__ __forceinline__ const _Float16* segB(int kt,
    const _Float16* wH, const _Float16* wL,
    const _Float16* uH, const _Float16* uL) {
  int s = kt >> 5;
  return s < 2 ? wH : s == 2 ? wL : s < 5 ? uH : uL;
}
#define K0OF(kt) (((kt) & 31) << 6)

__global__ __launch_bounds__(512, 2) void gemm_gates_kernel(
    const _Float16* __restrict__ xH, const _Float16* __restrict__ xL,
    const _Float16* __restrict__ hH, const _Float16* __restrict__ hL,
    const _Float16* __restrict__ wH, const _Float16* __restrict__ wL,
    const _Float16* __restrict__ uH, const _Float16* __restrict__ uL,
    const float* __restrict__ bias,
    float* __restrict__ out, _Float16* __restrict__ o_ws) {
  __shared__ _Float16 sA[2][256 * 64];   // 2 x 32 KiB
  __shared__ _Float16 sB[2][256 * 64];   // 2 x 32 KiB  (total 128 KiB)

  // XCD-aware swizzle: nwg = 1024 = 8 * 128.
  const int bid = blockIdx.x;
  const int wg = (bid & 7) * 128 + (bid >> 3);
  const int tm = wg >> 5;   // 0..31 (batch rows, 256 each)
  const int tn = wg & 31;   // 0..31 (output cols, 256 each)
  const int rowA = tm * 256;
  const int rowB = tn * 256;

  const int tid = threadIdx.x;
  const int w = tid >> 6;
  const int lane = tid & 63;
  const int wr = w >> 2;    // 0..1 : wave row half (128 rows)
  const int wc = w & 3;     // 0..3 : wave col quarter (64 cols)

  const int lrow = lane & 15;
  const int q = lane >> 4;
  const int swl = (lane & 7) << 4;
  // element offset within a 64-elem row for kk=0/1 (swizzled)
  const int co0 = (((0 << 6) | (q << 4)) ^ swl) >> 1;
  const int co1 = (((1 << 6) | (q << 4)) ^ swl) >> 1;

  f32x4 acc[8][4];
#pragma unroll
  for (int m = 0; m < 8; ++m)
#pragma unroll
    for (int n = 0; n < 4; ++n)
      acc[m][n] = (f32x4){0.f, 0.f, 0.f, 0.f};

  // Prologue: stage tile0 fully + tile1's A0,A1,B0  (7 halves, 14 loads)
  stage_half(segA(0, xH, xL, hH, hL), rowA, 0, sA[0], 0, tid);
  stage_half(segA(0, xH, xL, hH, hL), rowA, 0, sA[0], 1, tid);
  stage_half(segB(0, wH, wL, uH, uL), rowB, 0, sB[0], 0, tid);
  stage_half(segB(0, wH, wL, uH, uL), rowB, 0, sB[0], 1, tid);
  stage_half(segA(1, xH, xL, hH, hL), rowA, K0OF(1), sA[1], 0, tid);
  stage_half(segA(1, xH, xL, hH, hL), rowA, K0OF(1), sA[1], 1, tid);
  stage_half(segB(1, wH, wL, uH, uL), rowB, K0OF(1), sB[1], 0, tid);

  h8_t aF[8][2];
  h8_t bF[2][2];

  for (int t = 0; t < T_TILES; ++t) {
    const int cur = t & 1;
    const _Float16* aP = sA[cur];
    const _Float16* bP = sB[cur];

    // group-start sync: all but last 3 staged halves complete => tile t resident
    if (t == T_TILES - 1) { asm volatile("s_waitcnt vmcnt(0)" ::: "memory"); }
    else                  { asm volatile("s_waitcnt vmcnt(6)" ::: "memory"); }
    BARRIER();

    // ---- phase 0: read ALL A frags + B n0-1; MFMA quad (m0-3, n0-1) ----
#pragma unroll
    for (int m = 0; m < 8; ++m) {
      const _Float16* rp = aP + (wr * 128 + m * 16 + lrow) * 64;
      aF[m][0] = *reinterpret_cast<const h8_t*>(rp + co0);
      aF[m][1] = *reinterpret_cast<const h8_t*>(rp + co1);
    }
#pragma unroll
    for (int nn = 0; nn < 2; ++nn) {
      const _Float16* rp = bP + (wc * 64 + nn * 16 + lrow) * 64;
      bF[nn][0] = *reinterpret_cast<const h8_t*>(rp + co0);
      bF[nn][1] = *reinterpret_cast<const h8_t*>(rp + co1);
    }
    if (t + 1 < T_TILES)
      stage_half(segB(t + 1, wH, wL, uH, uL), rowB, K0OF(t + 1), sB[(t + 1) & 1], 1, tid);
    BARRIER();
    __builtin_amdgcn_s_setprio(1);
#pragma unroll
    for (int mm = 0; mm < 4; ++mm)
#pragma unroll
      for (int nn = 0; nn < 2; ++nn)
#pragma unroll
        for (int kk = 0; kk < 2; ++kk)
          acc[mm][nn] = __builtin_amdgcn_mfma_f32_16x16x32_f16(
              aF[mm][kk], bF[nn][kk], acc[mm][nn], 0, 0, 0);
    __builtin_amdgcn_s_setprio(0);
    BARRIER();

    // ---- phase 1: MFMA quad (m4-7, n0-1); stage A0(t+2) ----
    if (t + 2 < T_TILES)
      stage_half(segA(t + 2, xH, xL, hH, hL), rowA, K0OF(t + 2), sA[cur], 0, tid);
    BARRIER();
    __builtin_amdgcn_s_setprio(1);
#pragma unroll
    for (int mm = 0; mm < 4; ++mm)
#pragma unroll
      for (int nn = 0; nn < 2; ++nn)
#pragma unroll
        for (int kk = 0; kk < 2; ++kk)
          acc[4 + mm][nn] = __builtin_amdgcn_mfma_f32_16x16x32_f16(
              aF[4 + mm][kk], bF[nn][kk], acc[4 + mm][nn], 0, 0, 0);
    __builtin_amdgcn_s_setprio(0);
    BARRIER();

    // ---- phase 2: read B n2-3 (reuse bF regs); MFMA quad (m0-3, n2-3) ----
#pragma unroll
    for (int nn = 0; nn < 2; ++nn) {
      const _Float16* rp = bP + (wc * 64 + (2 + nn) * 16 + lrow) * 64;
      bF[nn][0] = *reinterpret_cast<const h8_t*>(rp + co0);
      bF[nn][1] = *reinterpret_cast<const h8_t*>(rp + co1);
    }
    if (t + 2 < T_TILES)
      stage_half(segA(t + 2, xH, xL, hH, hL), rowA, K0OF(t + 2), sA[cur], 1, tid);
    BARRIER();
    __builtin_amdgcn_s_setprio(1);
#pragma unroll
    for (int mm = 0; mm < 4; ++mm)
#pragma unroll
      for (int nn = 0; nn < 2; ++nn)
#pragma unroll
        for (int kk = 0; kk < 2; ++kk)
          acc[mm][2 + nn] = __builtin_amdgcn_mfma_f32_16x16x32_f16(
              aF[mm][kk], bF[nn][kk], acc[mm][2 + nn], 0, 0, 0);
    __builtin_amdgcn_s_setprio(0);
    BARRIER();

    // ---- phase 3: MFMA quad (m4-7, n2-3); stage B0(t+2) ----
    if (t + 2 < T_TILES)
      stage_half(segB(t + 2, wH, wL, uH, uL), rowB, K0OF(t + 2), sB[cur], 0, tid);
    BARRIER();
    __builtin_amdgcn_s_setprio(1);
#pragma unroll
    for (int mm = 0; mm < 4; ++mm)
#pragma unroll
      for (int nn = 0; nn < 2; ++nn)
#pragma unroll
        for (int kk = 0; kk < 2; ++kk)
          acc[4 + mm][2 + nn] = __builtin_amdgcn_mfma_f32_16x16x32_f16(
              aF[4 + mm][kk], bF[nn][kk], acc[4 + mm][2 + nn], 0, 0, 0);
    __builtin_amdgcn_s_setprio(0);
    // no trailing barrier: next group's vmcnt+barrier covers it
  }

  // ---- epilogue: activations, fused gate writes ----
  const int gate = tn >> 3;  // 8 n-tiles per gate
  const int row0 = tm * 256 + wr * 128 + (lane >> 4) * 4;
  const int col0 = tn * 256 + wc * 64 + (lane & 15);
#pragma unroll
  for (int n = 0; n < 4; ++n) {
    const int col = col0 + n * 16;
    const int hcol = col & 2047;
    const float bv = bias[col];
#pragma unroll
    for (int m = 0; m < 8; ++m) {
      const int row = row0 + m * 16;
#pragma unroll
      for (int r = 0; r < 4; ++r) {
        float v = acc[m][n][r] + bv;
        size_t oidx = (size_t)(row + r) * 2048 + hcol;
        if (gate == 0)       out[(size_t)3 * PLANE + oidx] = fast_sigmoid(v);  // f_t
        else if (gate == 1)  out[(size_t)2 * PLANE + oidx] = fast_sigmoid(v);  // i_t
        else if (gate == 2)  out[(size_t)4 * PLANE + oidx] = fast_tanh(v);     // C~_t
        else                 o_ws[oidx] = (_Float16)fast_sigmoid(v);           // o_t
      }
    }
  }
}

// ---------------- final: C_t and h_t ----------------
__global__ void final_kernel(const float* __restrict__ outr,
                             const float* __restrict__ C_prev,
                             const _Float16* __restrict__ o_ws,
                             float* __restrict__ out) {
  const float* iP = outr + (size_t)2 * PLANE;
  const float* fP = outr + (size_t)3 * PLANE;
  const float* cP = outr + (size_t)4 * PLANE;
  int idx = (blockIdx.x * blockDim.x + threadIdx.x) * 4;
  int stride = gridDim.x * blockDim.x * 4;
  for (int i = idx; i < PLANE; i += stride) {
    float4 fv = *reinterpret_cast<const float4*>(fP + i);
    float4 iv = *reinterpret_cast<const float4*>(iP + i);
    float4 cv = *reinterpret_cast<const float4*>(cP + i);
    float4 cp = *reinterpret_cast<const float4*>(C_prev + i);
    h4_t ov = *reinterpret_cast<const h4_t*>(o_ws + i);
    float4 C, H;
    C.x = fv.x * cp.x + iv.x * cv.x;
    C.y = fv.y * cp.y + iv.y * cv.y;
    C.z = fv.z * cp.z + iv.z * cv.z;
    C.w = fv.w * cp.w + iv.w * cv.w;
    H.x = (float)ov.x * fast_tanh(C.x);
    H.y = (float)ov.y * fast_tanh(C.y);
    H.z = (float)ov.z * fast_tanh(C.z);
    H.w = (float)ov.w * fast_tanh(C.w);
    *reinterpret_cast<float4*>(out + (size_t)PLANE + i) = C;  // C_t
    *reinterpret_cast<float4*>(out + i) = H;                  // h_t
  }
}

extern "C" void kernel_launch(void* const* d_in, const int* in_sizes, int n_in,
                              void* d_out, int out_size, void* d_ws, size_t ws_size,
                              hipStream_t stream) {
  const float* x  = (const float*)d_in[0];
  const float* hp = (const float*)d_in[1];
  const float* Cp = (const float*)d_in[2];
  const float* W  = (const float*)d_in[3];
  const float* U  = (const float*)d_in[4];
  const float* b  = (const float*)d_in[5];
  float* out = (float*)d_out;

  _Float16* ws = (_Float16*)d_ws;
  _Float16* xh = ws;
  _Float16* xl = xh + PLANE;
  _Float16* hh = xl + PLANE;
  _Float16* hl = hh + PLANE;
  _Float16* Wh = hl + PLANE;
  _Float16* Wl = Wh + PLANE;
  _Float16* Uh = Wl + PLANE;
  _Float16* Ul = Uh + PLANE;
  _Float16* o_ws = Ul + PLANE;  // total ws use: 9 * 32 MiB = 288 MiB

  dim3 blk(256);
  split_kernel<<<dim3(2048), blk, 0, stream>>>(x, xh, xl, PLANE);
  split_kernel<<<dim3(2048), blk, 0, stream>>>(hp, hh, hl, PLANE);
  split_kernel<<<dim3(2048), blk, 0, stream>>>(W, Wh, Wl, PLANE);
  split_kernel<<<dim3(2048), blk, 0, stream>>>(U, Uh, Ul, PLANE);
  gemm_gates_kernel<<<dim3(1024), dim3(512), 0, stream>>>(xh, xl, hh, hl,
                                                          Wh, Wl, Uh, Ul,
                                                          b, out, o_ws);
  final_kernel<<<dim3(2048), blk, 0, stream>>>(out, Cp, o_ws, out);
}

// Round 3
// 1851.185 us; speedup vs baseline: 1.3741x; 1.0812x over previous
//
#include <hip/hip_runtime.h>

// LSTM cell, B=8192, I=H=2048, fp32 in/out.
// fp16 hi/lo 3-term split GEMM on MFMA 16x16x32_f16.
// 256x256 tile, BK=64, 8 waves. Strict 1-ahead double buffer, 2 barriers +
// one counted vmcnt per K-tile, ds_reads/MFMA free-running within the tile.

#define PLANE 16777216   // 8192*2048 elements per [B,H] plane
#define T_TILES 192      // 6 segments x 32 K-tiles of 64

typedef _Float16 h8_t __attribute__((ext_vector_type(8)));
typedef _Float16 h4_t __attribute__((ext_vector_type(4)));
typedef float    f32x4 __attribute__((ext_vector_type(4)));

#define BARRIER() do { asm volatile("" ::: "memory"); \
                       __builtin_amdgcn_s_barrier();  \
                       asm volatile("" ::: "memory"); } while (0)

__device__ __forceinline__ float fast_sigmoid(float x) {
  return 1.0f / (1.0f + __expf(-x));
}
__device__ __forceinline__ float fast_tanh(float x) {
  float e = __expf(2.0f * x);
  return 1.0f - 2.0f / (e + 1.0f);
}

// ---------------- split: fp32 -> (hi, lo) fp16 ----------------
__global__ void split_kernel(const float* __restrict__ src,
                             _Float16* __restrict__ hi,
                             _Float16* __restrict__ lo, int n) {
  int idx = (blockIdx.x * blockDim.x + threadIdx.x) * 4;
  int stride = gridDim.x * blockDim.x * 4;
  for (int i = idx; i < n; i += stride) {
    float4 v = *reinterpret_cast<const float4*>(src + i);
    _Float16 h0 = (_Float16)v.x, h1 = (_Float16)v.y,
             h2 = (_Float16)v.z, h3 = (_Float16)v.w;
    h4_t hv = {h0, h1, h2, h3};
    h4_t lv = {(_Float16)(v.x - (float)h0), (_Float16)(v.y - (float)h1),
               (_Float16)(v.z - (float)h2), (_Float16)(v.w - (float)h3)};
    *reinterpret_cast<h4_t*>(hi + i) = hv;
    *reinterpret_cast<h4_t*>(lo + i) = lv;
  }
}

// ---------------- GEMM helpers ----------------
__device__ __forceinline__ void gload_lds16(const _Float16* g, _Float16* l) {
  __builtin_amdgcn_global_load_lds(
      (const __attribute__((address_space(1))) void*)g,
      (__attribute__((address_space(3))) void*)l, 16, 0, 0);
}

// Stage one half-tile (128 rows x 64 k f16 = 16KiB), pre-swizzled global
// source so LDS-linear dest + swizzled ds_read form a consistent involution.
__device__ __forceinline__ void stage_half(const _Float16* __restrict__ seg,
                                           int rowBase, int k0,
                                           _Float16* lds, int hh, int tid) {
#pragma unroll
  for (int j = 0; j < 2; ++j) {
    const int c = j * 512 + tid;          // 0..1023 16B-chunks
    const int r = c >> 3;                 // row in half 0..127
    const int colb = (c & 7) << 4;        // byte col 0..112
    const int sw = colb ^ ((r & 7) << 4); // involutive XOR swizzle
    const _Float16* g = seg + (size_t)(rowBase + hh * 128 + r) * 2048 + k0 + (sw >> 1);
    gload_lds16(g, lds + hh * 8192 + c * 8);
  }
}

__device__ __forceinline__ const _Float16* segA(int kt,
    const _Float16* xH, const _Float16* xL,
    const _Float16* hH, const _Float16* hL) {
  int s = kt >> 5;
  return s == 0 ? xH : s == 1 ? xL : s == 2 ? xH : s == 3 ? hH : s == 4 ? hL : hH;
}
__device__ __forceinline__ const _Float16* segB(int kt,
    const _Float16* wH, const _Float16* wL,
    const _Float16* uH, const _Float16* uL) {
  int s = kt >> 5;
  return s < 2 ? wH : s == 2 ? wL : s < 5 ? uH : uL;
}
#define K0OF(kt) (((kt) & 31) << 6)

__global__ __launch_bounds__(512, 2) void gemm_gates_kernel(
    const _Float16* __restrict__ xH, const _Float16* __restrict__ xL,
    const _Float16* __restrict__ hH, const _Float16* __restrict__ hL,
    const _Float16* __restrict__ wH, const _Float16* __restrict__ wL,
    const _Float16* __restrict__ uH, const _Float16* __restrict__ uL,
    const float* __restrict__ bias,
    float* __restrict__ out, _Float16* __restrict__ o_ws) {
  __shared__ _Float16 sA[2][256 * 64];   // 2 x 32 KiB
  __shared__ _Float16 sB[2][256 * 64];   // 2 x 32 KiB  (total 128 KiB)

  // XCD-aware swizzle: nwg = 1024 = 8 * 128.
  const int bid = blockIdx.x;
  const int wg = (bid & 7) * 128 + (bid >> 3);
  const int tm = wg >> 5;   // 0..31 (batch rows, 256 each)
  const int tn = wg & 31;   // 0..31 (output cols, 256 each)
  const int rowA = tm * 256;
  const int rowB = tn * 256;

  const int tid = threadIdx.x;
  const int w = tid >> 6;
  const int lane = tid & 63;
  const int wr = w >> 2;    // 0..1 : wave row half (128 rows)
  const int wc = w & 3;     // 0..3 : wave col quarter (64 cols)

  const int lrow = lane & 15;
  const int q = lane >> 4;
  const int swl = (lane & 7) << 4;
  // element offset within a 64-elem row for kk=0/1 (swizzled)
  const int co0 = (((0 << 6) | (q << 4)) ^ swl) >> 1;
  const int co1 = (((1 << 6) | (q << 4)) ^ swl) >> 1;

  f32x4 acc[8][4];
#pragma unroll
  for (int m = 0; m < 8; ++m)
#pragma unroll
    for (int n = 0; n < 4; ++n)
      acc[m][n] = (f32x4){0.f, 0.f, 0.f, 0.f};

  // Prologue: stage tile 0 fully (4 halves = 8 loads outstanding).
  stage_half(segA(0, xH, xL, hH, hL), rowA, 0, sA[0], 0, tid);
  stage_half(segA(0, xH, xL, hH, hL), rowA, 0, sA[0], 1, tid);
  stage_half(segB(0, wH, wL, uH, uL), rowB, 0, sB[0], 0, tid);
  stage_half(segB(0, wH, wL, uH, uL), rowB, 0, sB[0], 1, tid);

  h8_t aF[4][2];
  h8_t bN01[2][2], bN23[2][2];

  for (int t = 0; t < T_TILES; ++t) {
    const int cur = t & 1;
    const _Float16* aP = sA[cur];
    const _Float16* bP = sB[cur];
    const bool doStage = (t + 1 < T_TILES);
    const int tn1 = doStage ? t + 1 : t;
    const _Float16* sgA = segA(tn1, xH, xL, hH, hL);
    const _Float16* sgB = segB(tn1, wH, wL, uH, uL);
    const int k1 = K0OF(tn1);
    _Float16* dA = sA[cur ^ 1];
    _Float16* dB = sB[cur ^ 1];

    // top: issue first next-tile half BEFORE the wait (keeps vmcnt counted).
    if (doStage) stage_half(sgA, rowA, k1, dA, 0, tid);

    // wait: tile t's 4 halves retired; A0(t+1)'s 2 loads stay in flight.
    if (doStage) { asm volatile("s_waitcnt vmcnt(2)" ::: "memory"); }
    else         { asm volatile("s_waitcnt vmcnt(0)" ::: "memory"); }
    BARRIER();

    // ---- P0: read quad0 operands; stage A1(t+1); MFMA m0-3 x n0-1 ----
#pragma unroll
    for (int nn = 0; nn < 2; ++nn) {
      const _Float16* rp = bP + (wc * 64 + nn * 16 + lrow) * 64;
      bN01[nn][0] = *reinterpret_cast<const h8_t*>(rp + co0);
      bN01[nn][1] = *reinterpret_cast<const h8_t*>(rp + co1);
    }
#pragma unroll
    for (int m = 0; m < 4; ++m) {
      const _Float16* rp = aP + (wr * 128 + m * 16 + lrow) * 64;
      aF[m][0] = *reinterpret_cast<const h8_t*>(rp + co0);
      aF[m][1] = *reinterpret_cast<const h8_t*>(rp + co1);
    }
    if (doStage) stage_half(sgA, rowA, k1, dA, 1, tid);
    __builtin_amdgcn_s_setprio(1);
#pragma unroll
    for (int mm = 0; mm < 4; ++mm)
#pragma unroll
      for (int nn = 0; nn < 2; ++nn)
#pragma unroll
        for (int kk = 0; kk < 2; ++kk)
          acc[mm][nn] = __builtin_amdgcn_mfma_f32_16x16x32_f16(
              aF[mm][kk], bN01[nn][kk], acc[mm][nn], 0, 0, 0);
    __builtin_amdgcn_s_setprio(0);

    // ---- P1: read B n2-3; stage B0(t+1); MFMA m0-3 x n2-3 ----
#pragma unroll
    for (int nn = 0; nn < 2; ++nn) {
      const _Float16* rp = bP + (wc * 64 + (2 + nn) * 16 + lrow) * 64;
      bN23[nn][0] = *reinterpret_cast<const h8_t*>(rp + co0);
      bN23[nn][1] = *reinterpret_cast<const h8_t*>(rp + co1);
    }
    if (doStage) stage_half(sgB, rowB, k1, dB, 0, tid);
    __builtin_amdgcn_s_setprio(1);
#pragma unroll
    for (int mm = 0; mm < 4; ++mm)
#pragma unroll
      for (int nn = 0; nn < 2; ++nn)
#pragma unroll
        for (int kk = 0; kk < 2; ++kk)
          acc[mm][2 + nn] = __builtin_amdgcn_mfma_f32_16x16x32_f16(
              aF[mm][kk], bN23[nn][kk], acc[mm][2 + nn], 0, 0, 0);
    __builtin_amdgcn_s_setprio(0);

    // ---- P2: read A m4-7 (reuse aF regs); stage B1(t+1); MFMA m4-7 x n0-1 ----
#pragma unroll
    for (int m = 0; m < 4; ++m) {
      const _Float16* rp = aP + (wr * 128 + (4 + m) * 16 + lrow) * 64;
      aF[m][0] = *reinterpret_cast<const h8_t*>(rp + co0);
      aF[m][1] = *reinterpret_cast<const h8_t*>(rp + co1);
    }
    if (doStage) stage_half(sgB, rowB, k1, dB, 1, tid);
    __builtin_amdgcn_s_setprio(1);
#pragma unroll
    for (int mm = 0; mm < 4; ++mm)
#pragma unroll
      for (int nn = 0; nn < 2; ++nn)
#pragma unroll
        for (int kk = 0; kk < 2; ++kk)
          acc[4 + mm][nn] = __builtin_amdgcn_mfma_f32_16x16x32_f16(
              aF[mm][kk], bN01[nn][kk], acc[4 + mm][nn], 0, 0, 0);
    __builtin_amdgcn_s_setprio(0);

    // ---- P3: MFMA m4-7 x n2-3 ----
    __builtin_amdgcn_s_setprio(1);
#pragma unroll
    for (int mm = 0; mm < 4; ++mm)
#pragma unroll
      for (int nn = 0; nn < 2; ++nn)
#pragma unroll
        for (int kk = 0; kk < 2; ++kk)
          acc[4 + mm][2 + nn] = __builtin_amdgcn_mfma_f32_16x16x32_f16(
              aF[mm][kk], bN23[nn][kk], acc[4 + mm][2 + nn], 0, 0, 0);
    __builtin_amdgcn_s_setprio(0);

    // end-of-tile: all reads of buf[cur] retired before next tile's top-stage
    // targets buf[cur] (for t+2).
    BARRIER();
  }

  // ---- epilogue: activations, fused gate writes ----
  const int gate = tn >> 3;  // 8 n-tiles per gate
  const int row0 = tm * 256 + wr * 128 + (lane >> 4) * 4;
  const int col0 = tn * 256 + wc * 64 + (lane & 15);
#pragma unroll
  for (int n = 0; n < 4; ++n) {
    const int col = col0 + n * 16;
    const int hcol = col & 2047;
    const float bv = bias[col];
#pragma unroll
    for (int m = 0; m < 8; ++m) {
      const int row = row0 + m * 16;
#pragma unroll
      for (int r = 0; r < 4; ++r) {
        float v = acc[m][n][r] + bv;
        size_t oidx = (size_t)(row + r) * 2048 + hcol;
        if (gate == 0)       out[(size_t)3 * PLANE + oidx] = fast_sigmoid(v);  // f_t
        else if (gate == 1)  out[(size_t)2 * PLANE + oidx] = fast_sigmoid(v);  // i_t
        else if (gate == 2)  out[(size_t)4 * PLANE + oidx] = fast_tanh(v);     // C~_t
        else                 o_ws[oidx] = (_Float16)fast_sigmoid(v);           // o_t
      }
    }
  }
}

// ---------------- final: C_t and h_t ----------------
__global__ void final_kernel(const float* __restrict__ outr,
                             const float* __restrict__ C_prev,
                             const _Float16* __restrict__ o_ws,
                             float* __restrict__ out) {
  const float* iP = outr + (size_t)2 * PLANE;
  const float* fP = outr + (size_t)3 * PLANE;
  const float* cP = outr + (size_t)4 * PLANE;
  int idx = (blockIdx.x * blockDim.x + threadIdx.x) * 4;
  int stride = gridDim.x * blockDim.x * 4;
  for (int i = idx; i < PLANE; i += stride) {
    float4 fv = *reinterpret_cast<const float4*>(fP + i);
    float4 iv = *reinterpret_cast<const float4*>(iP + i);
    float4 cv = *reinterpret_cast<const float4*>(cP + i);
    float4 cp = *reinterpret_cast<const float4*>(C_prev + i);
    h4_t ov = *reinterpret_cast<const h4_t*>(o_ws + i);
    float4 C, H;
    C.x = fv.x * cp.x + iv.x * cv.x;
    C.y = fv.y * cp.y + iv.y * cv.y;
    C.z = fv.z * cp.z + iv.z * cv.z;
    C.w = fv.w * cp.w + iv.w * cv.w;
    H.x = (float)ov.x * fast_tanh(C.x);
    H.y = (float)ov.y * fast_tanh(C.y);
    H.z = (float)ov.z * fast_tanh(C.z);
    H.w = (float)ov.w * fast_tanh(C.w);
    *reinterpret_cast<float4*>(out + (size_t)PLANE + i) = C;  // C_t
    *reinterpret_cast<float4*>(out + i) = H;                  // h_t
  }
}

extern "C" void kernel_launch(void* const* d_in, const int* in_sizes, int n_in,
                              void* d_out, int out_size, void* d_ws, size_t ws_size,
                              hipStream_t stream) {
  const float* x  = (const float*)d_in[0];
  const float* hp = (const float*)d_in[1];
  const float* Cp = (const float*)d_in[2];
  const float* W  = (const float*)d_in[3];
  const float* U  = (const float*)d_in[4];
  const float* b  = (const float*)d_in[5];
  float* out = (float*)d_out;

  _Float16* ws = (_Float16*)d_ws;
  _Float16* xh = ws;
  _Float16* xl = xh + PLANE;
  _Float16* hh = xl + PLANE;
  _Float16* hl = hh + PLANE;
  _Float16* Wh = hl + PLANE;
  _Float16* Wl = Wh + PLANE;
  _Float16* Uh = Wl + PLANE;
  _Float16* Ul = Uh + PLANE;
  _Float16* o_ws = Ul + PLANE;  // total ws use: 9 * 32 MiB = 288 MiB

  dim3 blk(256);
  split_kernel<<<dim3(2048), blk, 0, stream>>>(x, xh, xl, PLANE);
  split_kernel<<<dim3(2048), blk, 0, stream>>>(hp, hh, hl, PLANE);
  split_kernel<<<dim3(2048), blk, 0, stream>>>(W, Wh, Wl, PLANE);
  split_kernel<<<dim3(2048), blk, 0, stream>>>(U, Uh, Ul, PLANE);
  gemm_gates_kernel<<<dim3(1024), dim3(512), 0, stream>>>(xh, xl, hh, hl,
                                                          Wh, Wl, Uh, Ul,
                                                          b, out, o_ws);
  final_kernel<<<dim3(2048), blk, 0, stream>>>(out, Cp, o_ws, out);
}